// Round 19
// baseline (51.527 us; speedup 1.0000x reference)
//
#include <hip/hip_runtime.h>
#include <hip/hip_bf16.h>

typedef __attribute__((ext_vector_type(8))) short short8;
typedef __attribute__((ext_vector_type(4))) float f32x4;
typedef __attribute__((ext_vector_type(4))) unsigned int u32x4;

#define GG 4
#define CC 128
#define HH 112
#define WW 112
#define HWSZ (HH * WW)
#define TH 16
#define TW 16
#define HALO 18
#define NPIX (HALO * HALO)      // 324
#define XSTR 32                 // NO pad: chunk byte = t*16 -> linear global_load_lds dest
#define HP 114                  // padded spatial dim (1-px zero border)
#define SLICE_PIX (HP * HP)
#define SLICE_ELE (SLICE_PIX * 32)
#define WK_ELEMS (4 * 9 * 16 * 32)
#define WP_ELEMS (4 * 2 * 16 * 32)
#define W_TOTAL (WK_ELEMS + WP_ELEMS)
#define XT_OFF 32768
#define XT_ELEMS (32 * SLICE_ELE)
#define WS_NEED ((size_t)(XT_OFF + XT_ELEMS) * 2)

// NOTE: bf16 pipeline only. Banned mechanisms (deterministic miscomputes):
//  - ds_bpermute after MFMA (r5/r9, absmax 9.16)
//  - f16 MFMA pipeline (r16, absmax 7.45)

__device__ __forceinline__ void reorder_one(int idx,
    const float* __restrict__ w_kg, const float* __restrict__ w_pw,
    unsigned short* __restrict__ ws)
{
    if (idx < WK_ELEMS) {
        int c = idx & 31, t = (idx >> 5) & 15, r = idx >> 9;
        int u = r % 9, g = r / 9;
        float v = (t < 9) ? w_kg[((g * 9 + t) * 32 + c) * 9 + u] : 0.0f;
        ws[idx] = __builtin_bit_cast(unsigned short, __float2bfloat16(v));
    } else if (idx < W_TOTAL) {
        int j = idx - WK_ELEMS;
        int c = j & 31, o = (j >> 5) & 15, mt = (j >> 9) & 1, g = j >> 10;
        float v = w_pw[(g * 32 + mt * 16 + o) * 32 + c];
        ws[idx] = __builtin_bit_cast(unsigned short, __float2bfloat16(v));
    }
}

__global__ __launch_bounds__(256)
void reorder_weights(const float* __restrict__ w_kg, const float* __restrict__ w_pw,
                     unsigned short* __restrict__ ws)
{
    reorder_one(blockIdx.x * 256 + threadIdx.x, w_kg, w_pw, ws);
}

// ---- transpose x -> padded x_t[b][g][114x114][c32] bf16;
//      hc==28: weights; hc==29: zero border ----
__global__ __launch_bounds__(256, 4)
void transpose_x(const float* __restrict__ x,
                 const float* __restrict__ w_kg, const float* __restrict__ w_pw,
                 unsigned short* __restrict__ ws)
{
    __shared__ unsigned int xsT[16 * 452];
    const int hc = blockIdx.x;
    const int g = blockIdx.y, b = blockIdx.z;
    const int tid = threadIdx.x;
    const int slice = b * GG + g;
    unsigned short* xt = ws + XT_OFF;

    if (hc == 28) {
        #pragma unroll
        for (int k = 0; k < 3; ++k) {
            int off = k * 256 + tid;
            if (off < 704)
                reorder_one(slice * 704 + off, w_kg, w_pw, ws);
        }
        return;
    }
    if (hc == 29) {
        unsigned short* xts = xt + (size_t)slice * SLICE_ELE;
        short8 z = {0, 0, 0, 0, 0, 0, 0, 0};
        #pragma unroll
        for (int k = 0; k < 2; ++k) {
            int i = tid + 256 * k;
            if (i < 452) {
                int pix;
                if (i < 114)      pix = i;
                else if (i < 228) pix = 113 * HP + (i - 114);
                else if (i < 340) pix = (i - 228 + 1) * HP;
                else              pix = (i - 340 + 1) * HP + 113;
                unsigned short* d = xts + (size_t)pix * 32;
                *(short8*)(d)      = z;
                *(short8*)(d + 8)  = z;
                *(short8*)(d + 16) = z;
                *(short8*)(d + 24) = z;
            }
        }
        return;
    }

    const float* xg = x + (size_t)(b * CC + g * 32) * HWSZ + hc * 4 * WW;

    unsigned short* xsT16 = (unsigned short*)xsT;
    #pragma unroll
    for (int k = 0; k < 14; ++k) {
        int t = tid + 256 * k;
        int c = (t * 37450) >> 22;
        int p4 = t - c * 112;
        float4 v = *(const float4*)(xg + (size_t)c * HWSZ + 4 * p4);
        int base = ((c >> 1) * 452 + 4 * p4) * 2 + (c & 1);
        xsT16[base + 0] = __builtin_bit_cast(unsigned short, __float2bfloat16(v.x));
        xsT16[base + 2] = __builtin_bit_cast(unsigned short, __float2bfloat16(v.y));
        xsT16[base + 4] = __builtin_bit_cast(unsigned short, __float2bfloat16(v.z));
        xsT16[base + 6] = __builtin_bit_cast(unsigned short, __float2bfloat16(v.w));
    }
    __syncthreads();

    unsigned short* xts = xt + (size_t)slice * SLICE_ELE;
    #pragma unroll
    for (int k = 0; k < 7; ++k) {
        int t = tid + 256 * k;
        int p = t >> 2, kb = t & 3;
        int row = p / 112;
        int col = p - 112 * row;
        unsigned r[4];
        #pragma unroll
        for (int j = 0; j < 4; ++j)
            r[j] = xsT[(4 * kb + j) * 452 + p];
        size_t pix = (size_t)(hc * 4 + row + 1) * HP + (col + 1);
        *(u32x4*)(xts + pix * 32 + kb * 8) = (u32x4){r[0], r[1], r[2], r[3]};
    }
}

// ---- per-thread weight fragments ----
struct Frags {
    short8 afrag[9];
    short8 wpfrag[2];
    float bkv[4];
    float bpv[8];
};

__device__ __forceinline__ void load_frags(Frags& f,
    const unsigned short* __restrict__ wsw,
    const float* __restrict__ b_kg, const float* __restrict__ b_pw,
    int g, int tid)
{
    const int lane = tid & 63;
    const int px   = lane & 15;
    const int kb   = lane >> 4;

    #pragma unroll
    for (int u = 0; u < 9; ++u)
        f.afrag[u] = *(const short8*)(wsw + (((g * 9 + u) * 16 + px) * 32 + kb * 8));
    #pragma unroll
    for (int mt = 0; mt < 2; ++mt)
        f.wpfrag[mt] = *(const short8*)(wsw + WK_ELEMS + (((g * 2 + mt) * 16 + px) * 32 + kb * 8));

    const float* bk = b_kg + g * 9;
    const float* bp = b_pw + g * 32;
    #pragma unroll
    for (int e = 0; e < 4; ++e) {
        int t = 4 * kb + e;
        f.bkv[e] = bk[t < 9 ? t : 0];
    }
    #pragma unroll
    for (int mt = 0; mt < 2; ++mt)
        #pragma unroll
        for (int e = 0; e < 4; ++e)
            f.bpv[mt * 4 + e] = bp[mt * 16 + 4 * kb + e];
}

// ---- bf16 compute body; unroll-2 r-loop (cross-iteration ILP over the serial
//      kvl-roundtrip chain); involution hi-operand unmasked (error ≤ 2^-9 rel) ----
__device__ __forceinline__ void compute_tile(const Frags& f,
    float* __restrict__ out, unsigned short* xs, float* kvl,
    int g, int b, int h0, int w0, int tid)
{
    const int lane = tid & 63;
    const int wid  = tid >> 6;
    const int px   = lane & 15;
    const int kb   = lane >> 4;

    float* kvp = &kvl[(wid * 16 + px) * 9];
    const size_t obase = ((size_t)(b * CC + g * 32) * HH + h0) * WW + w0 + px;

    #pragma unroll 2
    for (int r = 0; r < 4; ++r) {
        const int py = wid * 4 + r;

        short8 bfrag[9];
        #pragma unroll
        for (int u = 0; u < 9; ++u) {
            int q = (py + u / 3) * HALO + (px + u % 3);
            bfrag[u] = *(const short8*)&xs[q * XSTR + kb * 8];
        }

        f32x4 kv = {0.f, 0.f, 0.f, 0.f};
        #pragma unroll
        for (int u = 0; u < 9; ++u)
            kv = __builtin_amdgcn_mfma_f32_16x16x32_bf16(f.afrag[u], bfrag[u], kv, 0, 0, 0);

        // kv cross-lane roundtrip (+bias): lane holds taps 4*kb..4*kb+3 of pixel px
        if (kb < 2) {
            #pragma unroll
            for (int i = 0; i < 4; ++i)
                kvp[4 * kb + i] = kv[i] + f.bkv[i];
        } else if (kb == 2) {
            kvp[8] = kv[0] + f.bkv[0];
        }
        float kvv[9];
        #pragma unroll
        for (int t = 0; t < 9; ++t) kvv[t] = kvp[t];

        // involution: lo exact (shifted), hi approximate (unmasked low mantissa,
        // rel err <= 2^-9 << bf16's 2^-8 rounding; saves 36 v_and per iter)
        float m[8] = {0.f, 0.f, 0.f, 0.f, 0.f, 0.f, 0.f, 0.f};
        #pragma unroll
        for (int u = 0; u < 9; ++u) {
            u32x4 bu = __builtin_bit_cast(u32x4, bfrag[u]);
            #pragma unroll
            for (int w = 0; w < 4; ++w) {
                unsigned d = bu[w];
                float lo = __builtin_bit_cast(float, d << 16);
                float hi = __builtin_bit_cast(float, d);
                m[2 * w]     = fmaf(lo, kvv[u], m[2 * w]);
                m[2 * w + 1] = fmaf(hi, kvv[u], m[2 * w + 1]);
            }
        }

        unsigned pk[4];
        #pragma unroll
        for (int w = 0; w < 4; ++w) {
            unsigned slo = __builtin_bit_cast(unsigned short, __float2bfloat16(m[2 * w]));
            unsigned shi = __builtin_bit_cast(unsigned short, __float2bfloat16(m[2 * w + 1]));
            pk[w] = slo | (shi << 16);
        }
        short8 mfrag = __builtin_bit_cast(short8, (u32x4){pk[0], pk[1], pk[2], pk[3]});

        f32x4 zero = {0.f, 0.f, 0.f, 0.f};
        f32x4 o0 = __builtin_amdgcn_mfma_f32_16x16x32_bf16(f.wpfrag[0], mfrag, zero, 0, 0, 0);
        f32x4 o1 = __builtin_amdgcn_mfma_f32_16x16x32_bf16(f.wpfrag[1], mfrag, zero, 0, 0, 0);

        #pragma unroll
        for (int e = 0; e < 4; ++e) {
            int o = 4 * kb + e;
            out[obase + (size_t)o * HWSZ + (size_t)py * WW] = o0[e] + f.bpv[e];
            out[obase + (size_t)(o + 16) * HWSZ + (size_t)py * WW] = o1[e] + f.bpv[4 + e];
        }
    }
}

// ---- fast main kernel: DMA staging (r15-proven), co-resident LDS footprint ----
__global__ __launch_bounds__(256, 4)
void invol_mfma(const unsigned short* __restrict__ ws_all,
                const float* __restrict__ b_kg, const float* __restrict__ b_pw,
                float* __restrict__ out)
{
    __shared__ unsigned short xs[NPIX * XSTR];   // 20,736 B, linear: chunk t at byte t*16
    __shared__ float kvl[4 * 16 * 9];            //  2,304 B -> 23,040 total, 7 blocks/CU

    const int tile  = blockIdx.x;
    const int tileh = tile / 7;
    const int tilew = tile - tileh * 7;
    const int g = blockIdx.y;
    const int b = blockIdx.z;
    const int h0 = tileh * TH;
    const int w0 = tilew * TW;
    const int tid = threadIdx.x;

    // DMA first: critical-path loads enter the memory system earliest
    {
        const unsigned short* xti = ws_all + XT_OFF + (size_t)(b * GG + g) * SLICE_ELE;
        #pragma unroll
        for (int k = 0; k < 6; ++k) {
            int t = tid + 256 * k;
            if (t < 1296) {
                int q = t >> 2, kb2 = t & 3;
                int r = (q * 57) >> 10;          // q/18 for q<324
                int col = q - 18 * r;
                const unsigned short* src =
                    xti + ((size_t)((h0 + r) * HP + (w0 + col)) * 32 + kb2 * 8);
                __builtin_amdgcn_global_load_lds(src, &xs[t * 8], 16, 0, 0);
            }
        }
    }

    Frags f;
    load_frags(f, ws_all, b_kg, b_pw, g, tid);

    __syncthreads();   // drains vmcnt (DMA + frag loads) before compute

    compute_tile(f, out, xs, kvl, g, b, h0, w0, tid);
}

// ---- fallback main kernel (direct fp32 staging) for small ws ----
__global__ __launch_bounds__(256, 4)
void invol_mfma_fb(const float* __restrict__ x,
                   const float* __restrict__ b_kg, const float* __restrict__ b_pw,
                   const unsigned short* __restrict__ ws, float* __restrict__ out)
{
    __shared__ unsigned short xs[NPIX * XSTR];
    __shared__ float kvl[4 * 16 * 9];

    const int tile  = blockIdx.x;
    const int tileh = tile / 7;
    const int tilew = tile - tileh * 7;
    const int g = blockIdx.y;
    const int b = blockIdx.z;
    const int h0 = tileh * TH;
    const int w0 = tilew * TW;
    const int tid = threadIdx.x;

    Frags f;
    load_frags(f, ws, b_kg, b_pw, g, tid);

    {
        const float* xg = x + (size_t)(b * CC + g * 32) * HWSZ;
        int c = 0, q = tid;
        #pragma unroll
        for (int batch = 0; batch < 3; ++batch) {
            const int bn = (batch == 2) ? 13 : 14;
            float v[14];
            int pki[14];
            #pragma unroll
            for (int it = 0; it < bn; ++it) {
                const int itg = batch * 14 + it;
                const bool valid = (itg < 40) || (tid < 128);
                int r   = (q * 57) >> 10;
                int col = q - 18 * r;
                int gh = h0 - 1 + r;
                int gw = w0 - 1 + col;
                bool ok = valid && ((unsigned)gh < (unsigned)HH) && ((unsigned)gw < (unsigned)WW);
                int ghc = min(max(gh, 0), HH - 1);
                int gwc = min(max(gw, 0), WW - 1);
                int cc  = min(c, 31);
                float t = xg[(size_t)cc * HWSZ + ghc * WW + gwc];
                v[it]   = ok ? t : 0.0f;
                pki[it] = (c < 32) ? (q * XSTR + c) : 0;
                q += 256; if (q >= NPIX) { q -= NPIX; ++c; }
            }
            #pragma unroll
            for (int it = 0; it < bn; ++it) {
                unsigned short val = __builtin_bit_cast(unsigned short, __float2bfloat16(v[it]));
                if (pki[it] || it == 0) xs[pki[it]] = val;   // c==32 items skipped
            }
        }
    }
    __syncthreads();

    compute_tile(f, out, xs, kvl, g, b, h0, w0, tid);
}

extern "C" void kernel_launch(void* const* d_in, const int* in_sizes, int n_in,
                              void* d_out, int out_size, void* d_ws, size_t ws_size,
                              hipStream_t stream)
{
    const float* x    = (const float*)d_in[0];
    const float* w_kg = (const float*)d_in[1];
    const float* b_kg = (const float*)d_in[2];
    const float* w_pw = (const float*)d_in[3];
    const float* b_pw = (const float*)d_in[4];
    float* out = (float*)d_out;
    unsigned short* ws = (unsigned short*)d_ws;

    if (ws_size >= WS_NEED) {
        hipLaunchKernelGGL(transpose_x, dim3(30, GG, 8), dim3(256), 0, stream,
                           x, w_kg, w_pw, ws);
        hipLaunchKernelGGL(invol_mfma, dim3(49, GG, 8), dim3(256), 0, stream,
                           ws, b_kg, b_pw, out);
    } else {
        int pre_blocks = (W_TOTAL + 255) / 256;
        hipLaunchKernelGGL(reorder_weights, dim3(pre_blocks), dim3(256), 0, stream,
                           w_kg, w_pw, ws);
        hipLaunchKernelGGL(invol_mfma_fb, dim3(49, GG, 8), dim3(256), 0, stream,
                           x, b_kg, b_pw, ws, out);
    }
}

// Round 20
// 37.106 us; speedup vs baseline: 1.3886x; 1.3886x over previous
//
#include <hip/hip_runtime.h>
#include <hip/hip_bf16.h>

typedef __attribute__((ext_vector_type(8))) short short8;
typedef __attribute__((ext_vector_type(4))) float f32x4;
typedef __attribute__((ext_vector_type(4))) unsigned int u32x4;

#define GG 4
#define CC 128
#define HH 112
#define WW 112
#define HWSZ (HH * WW)
#define TH 16
#define TW 16
#define HALO 18
#define NPIX (HALO * HALO)      // 324
#define XSTR 32                 // chunk byte = slot*16 -> linear global_load_lds dest
#define HUS (NPIX * XSTR)       // ushorts per half-tile region (10368)
#define HP 114                  // padded spatial dim (1-px zero border)
#define SLICE_PIX (HP * HP)
#define SLICE_ELE (SLICE_PIX * 32)
#define WK_ELEMS (4 * 9 * 16 * 32)
#define WP_ELEMS (4 * 2 * 16 * 32)
#define W_TOTAL (WK_ELEMS + WP_ELEMS)
#define XT_OFF 32768
#define XT_ELEMS (32 * SLICE_ELE)
#define WS_NEED ((size_t)(XT_OFF + XT_ELEMS) * 2)

// NOTE: bf16 pipeline only. Banned mechanisms (deterministic miscomputes):
//  - ds_bpermute after MFMA (r5/r9, absmax 9.16)
//  - f16 MFMA pipeline (r16, absmax 7.45)
// Banned perf changes: unroll-2 r-loop (r19: VGPR spill, +28MB scratch writes);
// 512-thread blocks (r12/r13); LDS-free B-frags (r14); single-pass fp32 staging (r11).

__device__ __forceinline__ void reorder_one(int idx,
    const float* __restrict__ w_kg, const float* __restrict__ w_pw,
    unsigned short* __restrict__ ws)
{
    if (idx < WK_ELEMS) {
        int c = idx & 31, t = (idx >> 5) & 15, r = idx >> 9;
        int u = r % 9, g = r / 9;
        float v = (t < 9) ? w_kg[((g * 9 + t) * 32 + c) * 9 + u] : 0.0f;
        ws[idx] = __builtin_bit_cast(unsigned short, __float2bfloat16(v));
    } else if (idx < W_TOTAL) {
        int j = idx - WK_ELEMS;
        int c = j & 31, o = (j >> 5) & 15, mt = (j >> 9) & 1, g = j >> 10;
        float v = w_pw[(g * 32 + mt * 16 + o) * 32 + c];
        ws[idx] = __builtin_bit_cast(unsigned short, __float2bfloat16(v));
    }
}

__global__ __launch_bounds__(256)
void reorder_weights(const float* __restrict__ w_kg, const float* __restrict__ w_pw,
                     unsigned short* __restrict__ ws)
{
    reorder_one(blockIdx.x * 256 + threadIdx.x, w_kg, w_pw, ws);
}

// ---- transpose x -> padded x_t[b][g][114x114][c32] bf16;
//      hc==28: weights; hc==29: zero border ----
__global__ __launch_bounds__(256, 4)
void transpose_x(const float* __restrict__ x,
                 const float* __restrict__ w_kg, const float* __restrict__ w_pw,
                 unsigned short* __restrict__ ws)
{
    __shared__ unsigned int xsT[16 * 452];
    const int hc = blockIdx.x;
    const int g = blockIdx.y, b = blockIdx.z;
    const int tid = threadIdx.x;
    const int slice = b * GG + g;
    unsigned short* xt = ws + XT_OFF;

    if (hc == 28) {
        #pragma unroll
        for (int k = 0; k < 3; ++k) {
            int off = k * 256 + tid;
            if (off < 704)
                reorder_one(slice * 704 + off, w_kg, w_pw, ws);
        }
        return;
    }
    if (hc == 29) {
        unsigned short* xts = xt + (size_t)slice * SLICE_ELE;
        short8 z = {0, 0, 0, 0, 0, 0, 0, 0};
        #pragma unroll
        for (int k = 0; k < 2; ++k) {
            int i = tid + 256 * k;
            if (i < 452) {
                int pix;
                if (i < 114)      pix = i;
                else if (i < 228) pix = 113 * HP + (i - 114);
                else if (i < 340) pix = (i - 228 + 1) * HP;
                else              pix = (i - 340 + 1) * HP + 113;
                unsigned short* d = xts + (size_t)pix * 32;
                *(short8*)(d)      = z;
                *(short8*)(d + 8)  = z;
                *(short8*)(d + 16) = z;
                *(short8*)(d + 24) = z;
            }
        }
        return;
    }

    const float* xg = x + (size_t)(b * CC + g * 32) * HWSZ + hc * 4 * WW;

    unsigned short* xsT16 = (unsigned short*)xsT;
    #pragma unroll
    for (int k = 0; k < 14; ++k) {
        int t = tid + 256 * k;
        int c = (t * 37450) >> 22;
        int p4 = t - c * 112;
        float4 v = *(const float4*)(xg + (size_t)c * HWSZ + 4 * p4);
        int base = ((c >> 1) * 452 + 4 * p4) * 2 + (c & 1);
        xsT16[base + 0] = __builtin_bit_cast(unsigned short, __float2bfloat16(v.x));
        xsT16[base + 2] = __builtin_bit_cast(unsigned short, __float2bfloat16(v.y));
        xsT16[base + 4] = __builtin_bit_cast(unsigned short, __float2bfloat16(v.z));
        xsT16[base + 6] = __builtin_bit_cast(unsigned short, __float2bfloat16(v.w));
    }
    __syncthreads();

    unsigned short* xts = xt + (size_t)slice * SLICE_ELE;
    #pragma unroll
    for (int k = 0; k < 7; ++k) {
        int t = tid + 256 * k;
        int p = t >> 2, kb = t & 3;
        int row = p / 112;
        int col = p - 112 * row;
        unsigned r[4];
        #pragma unroll
        for (int j = 0; j < 4; ++j)
            r[j] = xsT[(4 * kb + j) * 452 + p];
        size_t pix = (size_t)(hc * 4 + row + 1) * HP + (col + 1);
        *(u32x4*)(xts + pix * 32 + kb * 8) = (u32x4){r[0], r[1], r[2], r[3]};
    }
}

// ---- per-thread weight fragments ----
struct Frags {
    short8 afrag[9];
    short8 wpfrag[2];
    float bkv[4];
    float bpv[8];
};

__device__ __forceinline__ void load_frags(Frags& f,
    const unsigned short* __restrict__ wsw,
    const float* __restrict__ b_kg, const float* __restrict__ b_pw,
    int g, int tid)
{
    const int lane = tid & 63;
    const int px   = lane & 15;
    const int kb   = lane >> 4;

    #pragma unroll
    for (int u = 0; u < 9; ++u)
        f.afrag[u] = *(const short8*)(wsw + (((g * 9 + u) * 16 + px) * 32 + kb * 8));
    #pragma unroll
    for (int mt = 0; mt < 2; ++mt)
        f.wpfrag[mt] = *(const short8*)(wsw + WK_ELEMS + (((g * 2 + mt) * 16 + px) * 32 + kb * 8));

    const float* bk = b_kg + g * 9;
    const float* bp = b_pw + g * 32;
    #pragma unroll
    for (int e = 0; e < 4; ++e) {
        int t = 4 * kb + e;
        f.bkv[e] = bk[t < 9 ? t : 0];
    }
    #pragma unroll
    for (int mt = 0; mt < 2; ++mt)
        #pragma unroll
        for (int e = 0; e < 4; ++e)
            f.bpv[mt * 4 + e] = bp[mt * 16 + 4 * kb + e];
}

// ---- r10/r15-proven bf16 compute body (kvl roundtrip, masked hi, unroll 1) ----
__device__ __forceinline__ void compute_tile(const Frags& f,
    float* __restrict__ out, const unsigned short* xs, float* kvl,
    int g, int bb, int h0, int w0, int tid)
{
    const int lane = tid & 63;
    const int wid  = tid >> 6;
    const int px   = lane & 15;
    const int kb   = lane >> 4;

    float* kvp = &kvl[(wid * 16 + px) * 12];
    const size_t obase = ((size_t)(bb * CC + g * 32) * HH + h0) * WW + w0 + px;

    #pragma unroll 1
    for (int r = 0; r < 4; ++r) {
        const int py = wid * 4 + r;

        short8 bfrag[9];
        #pragma unroll
        for (int u = 0; u < 9; ++u) {
            int q = (py + u / 3) * HALO + (px + u % 3);
            bfrag[u] = *(const short8*)&xs[q * XSTR + kb * 8];
        }

        f32x4 kv = {0.f, 0.f, 0.f, 0.f};
        #pragma unroll
        for (int u = 0; u < 9; ++u)
            kv = __builtin_amdgcn_mfma_f32_16x16x32_bf16(f.afrag[u], bfrag[u], kv, 0, 0, 0);

        if (kb < 2) {
            f32x4 kvb;
            #pragma unroll
            for (int i = 0; i < 4; ++i) kvb[i] = kv[i] + f.bkv[i];
            *(f32x4*)&kvp[4 * kb] = kvb;
        } else if (kb == 2) {
            kvp[8] = kv[0] + f.bkv[0];
        }
        f32x4 k03 = *(const f32x4*)&kvp[0];
        f32x4 k47 = *(const f32x4*)&kvp[4];
        float k8 = kvp[8];
        float kvv[9] = {k03.x, k03.y, k03.z, k03.w, k47.x, k47.y, k47.z, k47.w, k8};

        float m[8] = {0.f, 0.f, 0.f, 0.f, 0.f, 0.f, 0.f, 0.f};
        #pragma unroll
        for (int u = 0; u < 9; ++u) {
            u32x4 bu = __builtin_bit_cast(u32x4, bfrag[u]);
            #pragma unroll
            for (int w = 0; w < 4; ++w) {
                unsigned d = bu[w];
                float lo = __builtin_bit_cast(float, d << 16);
                float hi = __builtin_bit_cast(float, d & 0xffff0000u);
                m[2 * w]     = fmaf(lo, kvv[u], m[2 * w]);
                m[2 * w + 1] = fmaf(hi, kvv[u], m[2 * w + 1]);
            }
        }

        unsigned pk[4];
        #pragma unroll
        for (int w = 0; w < 4; ++w) {
            unsigned slo = __builtin_bit_cast(unsigned short, __float2bfloat16(m[2 * w]));
            unsigned shi = __builtin_bit_cast(unsigned short, __float2bfloat16(m[2 * w + 1]));
            pk[w] = slo | (shi << 16);
        }
        short8 mfrag = __builtin_bit_cast(short8, (u32x4){pk[0], pk[1], pk[2], pk[3]});

        f32x4 zero = {0.f, 0.f, 0.f, 0.f};
        f32x4 o0 = __builtin_amdgcn_mfma_f32_16x16x32_bf16(f.wpfrag[0], mfrag, zero, 0, 0, 0);
        f32x4 o1 = __builtin_amdgcn_mfma_f32_16x16x32_bf16(f.wpfrag[1], mfrag, zero, 0, 0, 0);

        #pragma unroll
        for (int e = 0; e < 4; ++e) {
            int o = 4 * kb + e;
            out[obase + (size_t)o * HWSZ + (size_t)py * WW] = o0[e] + f.bpv[e];
            out[obase + (size_t)(o + 16) * HWSZ + (size_t)py * WW] = o1[e] + f.bpv[4 + e];
        }
    }
}

// ---- fast main kernel: TWO batches per block (b = 2*bz, 2*bz+1), same (tile,g).
//      Frags loaded once; both halves' DMA issued before ONE barrier; each wave
//      then runs 8 r-iterations — prologue (stage-wait) amortized 2x. ----
__global__ __launch_bounds__(256, 4)
void invol_mfma(const unsigned short* __restrict__ ws_all,
                const float* __restrict__ b_kg, const float* __restrict__ b_pw,
                float* __restrict__ out)
{
    __shared__ unsigned short xs[2 * HUS];       // 41,472 B (two half-tile regions)
    __shared__ float kvl[4 * 16 * 12];           //  3,072 B -> 44.5 KB, 3 blocks/CU

    const int tile  = blockIdx.x;
    const int tileh = tile / 7;
    const int tilew = tile - tileh * 7;
    const int g  = blockIdx.y;
    const int bz = blockIdx.z;                   // 0..3 -> batches 2bz, 2bz+1
    const int h0 = tileh * TH;
    const int w0 = tilew * TW;
    const int tid = threadIdx.x;

    Frags f;
    load_frags(f, ws_all, b_kg, b_pw, g, tid);   // same g for both batches

    // staging: 2592 x 16B DMA chunks (1296 per half), linear dest per half
    {
        const unsigned short* xt0 =
            ws_all + XT_OFF + (size_t)(2 * bz * GG + g) * SLICE_ELE;
        #pragma unroll
        for (int k = 0; k < 11; ++k) {
            int t = tid + 256 * k;
            if (k < 10 || t < 2592) {
                int half = (t >= 1296) ? 1 : 0;
                int tq = t - half * 1296;
                int q = tq >> 2, kb2 = tq & 3;
                int r = (q * 57) >> 10;          // q/18 for q<324
                int col = q - 18 * r;
                const unsigned short* src = xt0
                    + (size_t)half * (GG * (size_t)SLICE_ELE)
                    + ((size_t)((h0 + r) * HP + (w0 + col)) * 32 + kb2 * 8);
                __builtin_amdgcn_global_load_lds(src, &xs[t * 8], 16, 0, 0);
            }
        }
    }
    __syncthreads();   // drains vmcnt (both halves' DMA + frag loads)

    compute_tile(f, out, xs,        kvl, g, 2 * bz,     h0, w0, tid);
    compute_tile(f, out, xs + HUS,  kvl, g, 2 * bz + 1, h0, w0, tid);
}

// ---- fallback main kernel (direct fp32 staging, per-(b,g) grid) ----
__global__ __launch_bounds__(256, 4)
void invol_mfma_fb(const float* __restrict__ x,
                   const float* __restrict__ b_kg, const float* __restrict__ b_pw,
                   const unsigned short* __restrict__ ws, float* __restrict__ out)
{
    __shared__ unsigned short xs[HUS];
    __shared__ float kvl[4 * 16 * 12];

    const int tile  = blockIdx.x;
    const int tileh = tile / 7;
    const int tilew = tile - tileh * 7;
    const int g = blockIdx.y;
    const int b = blockIdx.z;
    const int h0 = tileh * TH;
    const int w0 = tilew * TW;
    const int tid = threadIdx.x;

    Frags f;
    load_frags(f, ws, b_kg, b_pw, g, tid);

    {
        const float* xg = x + (size_t)(b * CC + g * 32) * HWSZ;
        int c = 0, q = tid;
        #pragma unroll
        for (int batch = 0; batch < 3; ++batch) {
            const int bn = (batch == 2) ? 13 : 14;
            float v[14];
            int pki[14];
            #pragma unroll
            for (int it = 0; it < bn; ++it) {
                const int itg = batch * 14 + it;
                const bool valid = (itg < 40) || (tid < 128);
                int r   = (q * 57) >> 10;
                int col = q - 18 * r;
                int gh = h0 - 1 + r;
                int gw = w0 - 1 + col;
                bool ok = valid && ((unsigned)gh < (unsigned)HH) && ((unsigned)gw < (unsigned)WW);
                int ghc = min(max(gh, 0), HH - 1);
                int gwc = min(max(gw, 0), WW - 1);
                int cc  = min(c, 31);
                float t = xg[(size_t)cc * HWSZ + ghc * WW + gwc];
                v[it]   = ok ? t : 0.0f;
                pki[it] = (c < 32) ? (q * XSTR + c) : 0;
                q += 256; if (q >= NPIX) { q -= NPIX; ++c; }
            }
            #pragma unroll
            for (int it = 0; it < bn; ++it) {
                unsigned short val = __builtin_bit_cast(unsigned short, __float2bfloat16(v[it]));
                if (pki[it] || it == 0) xs[pki[it]] = val;
            }
        }
    }
    __syncthreads();

    compute_tile(f, out, xs, kvl, g, b, h0, w0, tid);
}

extern "C" void kernel_launch(void* const* d_in, const int* in_sizes, int n_in,
                              void* d_out, int out_size, void* d_ws, size_t ws_size,
                              hipStream_t stream)
{
    const float* x    = (const float*)d_in[0];
    const float* w_kg = (const float*)d_in[1];
    const float* b_kg = (const float*)d_in[2];
    const float* w_pw = (const float*)d_in[3];
    const float* b_pw = (const float*)d_in[4];
    float* out = (float*)d_out;
    unsigned short* ws = (unsigned short*)d_ws;

    if (ws_size >= WS_NEED) {
        hipLaunchKernelGGL(transpose_x, dim3(30, GG, 8), dim3(256), 0, stream,
                           x, w_kg, w_pw, ws);
        hipLaunchKernelGGL(invol_mfma, dim3(49, GG, 4), dim3(256), 0, stream,
                           ws, b_kg, b_pw, out);
    } else {
        int pre_blocks = (W_TOTAL + 255) / 256;
        hipLaunchKernelGGL(reorder_weights, dim3(pre_blocks), dim3(256), 0, stream,
                           w_kg, w_pw, ws);
        hipLaunchKernelGGL(invol_mfma_fb, dim3(49, GG, 8), dim3(256), 0, stream,
                           x, b_kg, b_pw, ws, out);
    }
}

// Round 21
// 35.348 us; speedup vs baseline: 1.4577x; 1.0497x over previous
//
#include <hip/hip_runtime.h>
#include <hip/hip_bf16.h>

typedef __attribute__((ext_vector_type(8))) short short8;
typedef __attribute__((ext_vector_type(4))) float f32x4;
typedef __attribute__((ext_vector_type(4))) unsigned int u32x4;

#define GG 4
#define CC 128
#define HH 112
#define WW 112
#define HWSZ (HH * WW)
#define TH 16
#define TW 16
#define HALO 18
#define NPIX (HALO * HALO)      // 324
#define XSTR 32                 // NO pad: chunk byte = t*16 -> linear global_load_lds dest
#define HP 114                  // padded spatial dim (1-px zero border)
#define SLICE_PIX (HP * HP)
#define SLICE_ELE (SLICE_PIX * 32)
#define WK_ELEMS (4 * 9 * 16 * 32)
#define WP_ELEMS (4 * 2 * 16 * 32)
#define W_TOTAL (WK_ELEMS + WP_ELEMS)
#define XT_OFF 32768
#define XT_ELEMS (32 * SLICE_ELE)
#define WS_NEED ((size_t)(XT_OFF + XT_ELEMS) * 2)

// Champion configuration (r15, 35.3 us). Banned mechanisms (deterministic
// miscomputes): ds_bpermute after MFMA (r5/r9); f16 MFMA pipeline (r16).
// Falsified perf levers: occupancy (r17), barrier-free staging (r18),
// unroll-2 (r19 spill), 2-batch amortization (r20), LDS-free B-frags (r14),
// 512-thread blocks (r12/r13), single-pass fp32 staging (r11).

__device__ __forceinline__ void reorder_one(int idx,
    const float* __restrict__ w_kg, const float* __restrict__ w_pw,
    unsigned short* __restrict__ ws)
{
    if (idx < WK_ELEMS) {
        int c = idx & 31, t = (idx >> 5) & 15, r = idx >> 9;
        int u = r % 9, g = r / 9;
        float v = (t < 9) ? w_kg[((g * 9 + t) * 32 + c) * 9 + u] : 0.0f;
        ws[idx] = __builtin_bit_cast(unsigned short, __float2bfloat16(v));
    } else if (idx < W_TOTAL) {
        int j = idx - WK_ELEMS;
        int c = j & 31, o = (j >> 5) & 15, mt = (j >> 9) & 1, g = j >> 10;
        float v = w_pw[(g * 32 + mt * 16 + o) * 32 + c];
        ws[idx] = __builtin_bit_cast(unsigned short, __float2bfloat16(v));
    }
}

__global__ __launch_bounds__(256)
void reorder_weights(const float* __restrict__ w_kg, const float* __restrict__ w_pw,
                     unsigned short* __restrict__ ws)
{
    reorder_one(blockIdx.x * 256 + threadIdx.x, w_kg, w_pw, ws);
}

// ---- transpose x -> padded x_t[b][g][114x114][c32] bf16;
//      hc==28: weights; hc==29: zero border ----
__global__ __launch_bounds__(256, 4)
void transpose_x(const float* __restrict__ x,
                 const float* __restrict__ w_kg, const float* __restrict__ w_pw,
                 unsigned short* __restrict__ ws)
{
    __shared__ unsigned int xsT[16 * 452];
    const int hc = blockIdx.x;
    const int g = blockIdx.y, b = blockIdx.z;
    const int tid = threadIdx.x;
    const int slice = b * GG + g;
    unsigned short* xt = ws + XT_OFF;

    if (hc == 28) {
        #pragma unroll
        for (int k = 0; k < 3; ++k) {
            int off = k * 256 + tid;
            if (off < 704)
                reorder_one(slice * 704 + off, w_kg, w_pw, ws);
        }
        return;
    }
    if (hc == 29) {
        unsigned short* xts = xt + (size_t)slice * SLICE_ELE;
        short8 z = {0, 0, 0, 0, 0, 0, 0, 0};
        #pragma unroll
        for (int k = 0; k < 2; ++k) {
            int i = tid + 256 * k;
            if (i < 452) {
                int pix;
                if (i < 114)      pix = i;
                else if (i < 228) pix = 113 * HP + (i - 114);
                else if (i < 340) pix = (i - 228 + 1) * HP;
                else              pix = (i - 340 + 1) * HP + 113;
                unsigned short* d = xts + (size_t)pix * 32;
                *(short8*)(d)      = z;
                *(short8*)(d + 8)  = z;
                *(short8*)(d + 16) = z;
                *(short8*)(d + 24) = z;
            }
        }
        return;
    }

    const float* xg = x + (size_t)(b * CC + g * 32) * HWSZ + hc * 4 * WW;

    unsigned short* xsT16 = (unsigned short*)xsT;
    #pragma unroll
    for (int k = 0; k < 14; ++k) {
        int t = tid + 256 * k;
        int c = (t * 37450) >> 22;
        int p4 = t - c * 112;
        float4 v = *(const float4*)(xg + (size_t)c * HWSZ + 4 * p4);
        int base = ((c >> 1) * 452 + 4 * p4) * 2 + (c & 1);
        xsT16[base + 0] = __builtin_bit_cast(unsigned short, __float2bfloat16(v.x));
        xsT16[base + 2] = __builtin_bit_cast(unsigned short, __float2bfloat16(v.y));
        xsT16[base + 4] = __builtin_bit_cast(unsigned short, __float2bfloat16(v.z));
        xsT16[base + 6] = __builtin_bit_cast(unsigned short, __float2bfloat16(v.w));
    }
    __syncthreads();

    unsigned short* xts = xt + (size_t)slice * SLICE_ELE;
    #pragma unroll
    for (int k = 0; k < 7; ++k) {
        int t = tid + 256 * k;
        int p = t >> 2, kb = t & 3;
        int row = p / 112;
        int col = p - 112 * row;
        unsigned r[4];
        #pragma unroll
        for (int j = 0; j < 4; ++j)
            r[j] = xsT[(4 * kb + j) * 452 + p];
        size_t pix = (size_t)(hc * 4 + row + 1) * HP + (col + 1);
        *(u32x4*)(xts + pix * 32 + kb * 8) = (u32x4){r[0], r[1], r[2], r[3]};
    }
}

// ---- per-thread weight fragments ----
struct Frags {
    short8 afrag[9];
    short8 wpfrag[2];
    float bkv[4];
    float bpv[8];
};

__device__ __forceinline__ void load_frags(Frags& f,
    const unsigned short* __restrict__ wsw,
    const float* __restrict__ b_kg, const float* __restrict__ b_pw,
    int g, int tid)
{
    const int lane = tid & 63;
    const int px   = lane & 15;
    const int kb   = lane >> 4;

    #pragma unroll
    for (int u = 0; u < 9; ++u)
        f.afrag[u] = *(const short8*)(wsw + (((g * 9 + u) * 16 + px) * 32 + kb * 8));
    #pragma unroll
    for (int mt = 0; mt < 2; ++mt)
        f.wpfrag[mt] = *(const short8*)(wsw + WK_ELEMS + (((g * 2 + mt) * 16 + px) * 32 + kb * 8));

    const float* bk = b_kg + g * 9;
    const float* bp = b_pw + g * 32;
    #pragma unroll
    for (int e = 0; e < 4; ++e) {
        int t = 4 * kb + e;
        f.bkv[e] = bk[t < 9 ? t : 0];
    }
    #pragma unroll
    for (int mt = 0; mt < 2; ++mt)
        #pragma unroll
        for (int e = 0; e < 4; ++e)
            f.bpv[mt * 4 + e] = bp[mt * 16 + 4 * kb + e];
}

// ---- r10-proven compute body (kvl roundtrip; NO ds_bpermute; no explicit waitcnt) ----
__device__ __forceinline__ void compute_tile(const Frags& f,
    float* __restrict__ out, unsigned short* xs, float* kvl,
    int g, int b, int h0, int w0, int tid)
{
    const int lane = tid & 63;
    const int wid  = tid >> 6;
    const int px   = lane & 15;
    const int kb   = lane >> 4;

    float* kvp = &kvl[(wid * 16 + px) * 12];
    const size_t obase = ((size_t)(b * CC + g * 32) * HH + h0) * WW + w0 + px;

    #pragma unroll 1
    for (int r = 0; r < 4; ++r) {
        const int py = wid * 4 + r;

        short8 bfrag[9];
        #pragma unroll
        for (int u = 0; u < 9; ++u) {
            int q = (py + u / 3) * HALO + (px + u % 3);
            bfrag[u] = *(const short8*)&xs[q * XSTR + kb * 8];
        }

        f32x4 kv = {0.f, 0.f, 0.f, 0.f};
        #pragma unroll
        for (int u = 0; u < 9; ++u)
            kv = __builtin_amdgcn_mfma_f32_16x16x32_bf16(f.afrag[u], bfrag[u], kv, 0, 0, 0);

        if (kb < 2) {
            f32x4 kvb;
            #pragma unroll
            for (int i = 0; i < 4; ++i) kvb[i] = kv[i] + f.bkv[i];
            *(f32x4*)&kvp[4 * kb] = kvb;
        } else if (kb == 2) {
            kvp[8] = kv[0] + f.bkv[0];
        }
        f32x4 k03 = *(const f32x4*)&kvp[0];
        f32x4 k47 = *(const f32x4*)&kvp[4];
        float k8 = kvp[8];
        float kvv[9] = {k03.x, k03.y, k03.z, k03.w, k47.x, k47.y, k47.z, k47.w, k8};

        float m[8] = {0.f, 0.f, 0.f, 0.f, 0.f, 0.f, 0.f, 0.f};
        #pragma unroll
        for (int u = 0; u < 9; ++u) {
            u32x4 bu = __builtin_bit_cast(u32x4, bfrag[u]);
            #pragma unroll
            for (int w = 0; w < 4; ++w) {
                unsigned d = bu[w];
                float lo = __builtin_bit_cast(float, d << 16);
                float hi = __builtin_bit_cast(float, d & 0xffff0000u);
                m[2 * w]     = fmaf(lo, kvv[u], m[2 * w]);
                m[2 * w + 1] = fmaf(hi, kvv[u], m[2 * w + 1]);
            }
        }

        unsigned pk[4];
        #pragma unroll
        for (int w = 0; w < 4; ++w) {
            unsigned slo = __builtin_bit_cast(unsigned short, __float2bfloat16(m[2 * w]));
            unsigned shi = __builtin_bit_cast(unsigned short, __float2bfloat16(m[2 * w + 1]));
            pk[w] = slo | (shi << 16);
        }
        short8 mfrag = __builtin_bit_cast(short8, (u32x4){pk[0], pk[1], pk[2], pk[3]});

        f32x4 zero = {0.f, 0.f, 0.f, 0.f};
        f32x4 o0 = __builtin_amdgcn_mfma_f32_16x16x32_bf16(f.wpfrag[0], mfrag, zero, 0, 0, 0);
        f32x4 o1 = __builtin_amdgcn_mfma_f32_16x16x32_bf16(f.wpfrag[1], mfrag, zero, 0, 0, 0);

        #pragma unroll
        for (int e = 0; e < 4; ++e) {
            int o = 4 * kb + e;
            out[obase + (size_t)o * HWSZ + (size_t)py * WW] = o0[e] + f.bpv[e];
            out[obase + (size_t)(o + 16) * HWSZ + (size_t)py * WW] = o1[e] + f.bpv[4 + e];
        }
    }
}

// ---- fast main kernel: global_load_lds DMA staging from padded x_t ----
__global__ __launch_bounds__(256, 4)
void invol_mfma(const unsigned short* __restrict__ ws_all,
                const float* __restrict__ b_kg, const float* __restrict__ b_pw,
                float* __restrict__ out)
{
    __shared__ unsigned short xs[NPIX * XSTR];   // 20,736 B, linear: chunk t at byte t*16
    __shared__ float kvl[4 * 16 * 12];           //  3,072 B

    const int tile  = blockIdx.x;
    const int tileh = tile / 7;
    const int tilew = tile - tileh * 7;
    const int g = blockIdx.y;
    const int b = blockIdx.z;
    const int h0 = tileh * TH;
    const int w0 = tilew * TW;
    const int tid = threadIdx.x;

    Frags f;
    load_frags(f, ws_all, b_kg, b_pw, g, tid);

    // staging: 1296 x 16B async DMA chunks. LDS dest byte = t*16 (uniform base +
    // lane*16 per wave-instr — HW requirement); source per-lane in padded x_t
    // (zero border -> no masking needed).
    {
        const unsigned short* xti = ws_all + XT_OFF + (size_t)(b * GG + g) * SLICE_ELE;
        #pragma unroll
        for (int k = 0; k < 6; ++k) {
            int t = tid + 256 * k;
            if (t < 1296) {
                int q = t >> 2, kb2 = t & 3;
                int r = (q * 57) >> 10;          // q/18 for q<324
                int col = q - 18 * r;
                const unsigned short* src =
                    xti + ((size_t)((h0 + r) * HP + (w0 + col)) * 32 + kb2 * 8);
                __builtin_amdgcn_global_load_lds(src, &xs[t * 8], 16, 0, 0);
            }
        }
    }
    __syncthreads();   // drains vmcnt (DMA + frag loads) before compute

    compute_tile(f, out, xs, kvl, g, b, h0, w0, tid);
}

// ---- fallback main kernel (direct fp32 staging) for small ws ----
__global__ __launch_bounds__(256, 4)
void invol_mfma_fb(const float* __restrict__ x,
                   const float* __restrict__ b_kg, const float* __restrict__ b_pw,
                   const unsigned short* __restrict__ ws, float* __restrict__ out)
{
    __shared__ unsigned short xs[NPIX * XSTR];
    __shared__ float kvl[4 * 16 * 12];

    const int tile  = blockIdx.x;
    const int tileh = tile / 7;
    const int tilew = tile - tileh * 7;
    const int g = blockIdx.y;
    const int b = blockIdx.z;
    const int h0 = tileh * TH;
    const int w0 = tilew * TW;
    const int tid = threadIdx.x;

    Frags f;
    load_frags(f, ws, b_kg, b_pw, g, tid);

    {
        const float* xg = x + (size_t)(b * CC + g * 32) * HWSZ;
        int c = 0, q = tid;
        #pragma unroll
        for (int batch = 0; batch < 3; ++batch) {
            const int bn = (batch == 2) ? 13 : 14;
            float v[14];
            int pki[14];
            #pragma unroll
            for (int it = 0; it < bn; ++it) {
                const int itg = batch * 14 + it;
                const bool valid = (itg < 40) || (tid < 128);
                int r   = (q * 57) >> 10;
                int col = q - 18 * r;
                int gh = h0 - 1 + r;
                int gw = w0 - 1 + col;
                bool ok = valid && ((unsigned)gh < (unsigned)HH) && ((unsigned)gw < (unsigned)WW);
                int ghc = min(max(gh, 0), HH - 1);
                int gwc = min(max(gw, 0), WW - 1);
                int cc  = min(c, 31);
                float t = xg[(size_t)cc * HWSZ + ghc * WW + gwc];
                v[it]   = ok ? t : 0.0f;
                pki[it] = (c < 32) ? (q * XSTR + c) : 0;
                q += 256; if (q >= NPIX) { q -= NPIX; ++c; }
            }
            #pragma unroll
            for (int it = 0; it < bn; ++it) {
                unsigned short val = __builtin_bit_cast(unsigned short, __float2bfloat16(v[it]));
                if (pki[it] || it == 0) xs[pki[it]] = val;   // c==32 items skipped
            }
        }
    }
    __syncthreads();

    compute_tile(f, out, xs, kvl, g, b, h0, w0, tid);
}

extern "C" void kernel_launch(void* const* d_in, const int* in_sizes, int n_in,
                              void* d_out, int out_size, void* d_ws, size_t ws_size,
                              hipStream_t stream)
{
    const float* x    = (const float*)d_in[0];
    const float* w_kg = (const float*)d_in[1];
    const float* b_kg = (const float*)d_in[2];
    const float* w_pw = (const float*)d_in[3];
    const float* b_pw = (const float*)d_in[4];
    float* out = (float*)d_out;
    unsigned short* ws = (unsigned short*)d_ws;

    if (ws_size >= WS_NEED) {
        hipLaunchKernelGGL(transpose_x, dim3(30, GG, 8), dim3(256), 0, stream,
                           x, w_kg, w_pw, ws);
        hipLaunchKernelGGL(invol_mfma, dim3(49, GG, 8), dim3(256), 0, stream,
                           ws, b_kg, b_pw, out);
    } else {
        int pre_blocks = (W_TOTAL + 255) / 256;
        hipLaunchKernelGGL(reorder_weights, dim3(pre_blocks), dim3(256), 0, stream,
                           w_kg, w_pw, ws);
        hipLaunchKernelGGL(invol_mfma_fb, dim3(49, GG, 8), dim3(256), 0, stream,
                           x, b_kg, b_pw, ws, out);
    }
}